// Round 5
// baseline (5273.528 us; speedup 1.0000x reference)
//
#include <hip/hip_runtime.h>
#include <stdint.h>

typedef unsigned short u16;
typedef short short8 __attribute__((ext_vector_type(8)));
typedef unsigned short u16x8 __attribute__((ext_vector_type(8)));
typedef float f32x4 __attribute__((ext_vector_type(4)));

#define MFMA16x16x32 __builtin_amdgcn_mfma_f32_16x16x32_bf16

#define L0SLOT (64*768)          // u16 elements per time-slot (64 batch x 768)
#define R0S 8                    // l0 ring depth (slots)
// ws layout (bytes): [0,4) mode | [256,12544) flags 96x32 ints | l0 ring | l1 ring
#define WS_FLAGS_OFF 256
#define WS_L0_OFF    12544
#define WS_L1_OFF    (12544 + R0S*L0SLOT*2)      // l1 ring: 2 slots

static __device__ __forceinline__ float bf2f(u16 u){
  union{unsigned int i; float f;} v; v.i=((unsigned int)u)<<16; return v.f;
}
static __device__ __forceinline__ u16 f2bf(float f){
  union{float f; unsigned int i;} v; v.f=f;
  return (u16)((v.i + 0x7fffu + ((v.i>>16)&1u))>>16);   // RNE
}
static __device__ __forceinline__ float sigf(float x){
  return __fdividef(1.f, 1.f + __expf(-x));
}
static __device__ __forceinline__ float tanh_(float x){
  return 1.f - __fdividef(2.f, __expf(2.f*x) + 1.f);
}
// mode: 1 = tensor is fp32 (convert on load), 0 = tensor is bf16
static __device__ __forceinline__ void stage8(u16* dst, const void* base, long e, int mode){
  if (mode==0){
    *(u16x8*)dst = *(const u16x8*)((const u16*)base + e);
  } else {
    const float* p = (const float*)base + e;
    float4 a = *(const float4*)p, b = *(const float4*)(p+4);
    u16x8 v; v[0]=f2bf(a.x); v[1]=f2bf(a.y); v[2]=f2bf(a.z); v[3]=f2bf(a.w);
    v[4]=f2bf(b.x); v[5]=f2bf(b.y); v[6]=f2bf(b.z); v[7]=f2bf(b.w);
    *(u16x8*)dst = v;
  }
}
static __device__ __forceinline__ short8 ldw8(const void* base, long e, int mode){
  if (mode==0) return *(const short8*)((const u16*)base + e);
  const float* p = (const float*)base + e;
  float4 a = *(const float4*)p, b = *(const float4*)(p+4);
  short8 r; r[0]=(short)f2bf(a.x); r[1]=(short)f2bf(a.y); r[2]=(short)f2bf(a.z); r[3]=(short)f2bf(a.w);
  r[4]=(short)f2bf(b.x); r[5]=(short)f2bf(b.y); r[6]=(short)f2bf(b.z); r[7]=(short)f2bf(b.w);
  return r;
}
static __device__ __forceinline__ float lds1(const void* base, long e, int mode){
  return mode ? ((const float*)base)[e] : bf2f(((const u16*)base)[e]);
}

// ---- Kd: dtype detection on raw W_emb words (kept as cheap insurance). -----
__global__ void kdet(const unsigned int* __restrict__ w, int* wsmode){
  __shared__ int sh[256];
  int c = 0;
  for (int i=threadIdx.x; i<4096; i+=256){
    unsigned int x = w[i] & 0xFFFFu;
    if (((x>>7)&0xFFu) >= 0x80u) c++;
  }
  sh[threadIdx.x]=c; __syncthreads();
  for (int s=128;s>0;s>>=1){
    if (threadIdx.x<s) sh[threadIdx.x]+=sh[threadIdx.x+s];
    __syncthreads();
  }
  if (threadIdx.x==0) wsmode[0] = (sh[0] > 256) ? 1 : 0;
}

// ---- K0: zero ring slot-0s + flags (ws re-poisoned 0xAA before every call) --
__global__ void k0_init(unsigned int* l0, unsigned int* l1, int* flags){
  int i = blockIdx.x*256 + threadIdx.x;       // 24576 threads
  l0[i] = 0u;                                 // l0 ring slot 0 (24576 dwords)
  l1[i] = 0u; l1[i + 24576] = 0u;             // both l1 slots
  if (i < 3072) flags[i] = 0;                 // 96 flags, 128B-strided
}

// ---- K3: persistent 4-chain LSTM, unified K=1152 cells, ring buffers -------
// 96 WGs x 256. wg 0..47: layer-0 (d=wg/24, slot=wg%24); wg 48..95: layer-1.
// gates[16 x 64] = W[16 gate-rows x 1152] @ act[1152 x 64],
// act = [input(768) | own-h(384)]. Weights register-resident as MFMA A-frags
// (gate rows on M => lane's 4 acc regs = i,f,g,o of one (hdim,batch));
// c stays fp32 in registers for all 200 steps. h histories: bf16 rings
// (l0 8-slot w/ layer-1 back-pressure, l1 2-slot). Target rows (pos[b]==t)
// written straight to out as FP32 (pre-rounding h).
__global__ __launch_bounds__(256,1) void k3_lstm(
    const void* __restrict__ wih, const void* __restrict__ whh,
    const void* __restrict__ blstm, const void* __restrict__ emb,
    const int* __restrict__ ctx, const int* __restrict__ pos,
    u16* __restrict__ l0r, u16* __restrict__ l1r, int* flags,
    const int* __restrict__ wsmode, float* __restrict__ out){
  __shared__ __align__(16) u16 lact[64*392];   // act chunk [64 batch][384+8 pad]
  __shared__ __align__(16) u16 hstage[64*16];
  __shared__ int stok[64];
  __shared__ int spos[64];
  const int mode = wsmode[0];
  const int tid = threadIdx.x, lane = tid & 63, w = tid >> 6;
  const int m15 = lane & 15, q = lane >> 4;
  const int wg = blockIdx.x;
  const int layer = (wg >= 48) ? 1 : 0;
  const int x = wg - layer*48;
  const int d = x / 24, slot = x % 24;
  const int kidx = 2*layer + d;
  const int j0 = slot*16 + w*4;                // this wave's 4 h-dims
  const int g = m15 & 3, hl = m15 >> 2;        // A-row m15 -> (gate, hdim)

  if (tid < 64) spos[tid] = pos[tid];
  const void* wihd = mode ? (const void*)((const float*)wih + (long)kidx*1536*768)
                          : (const void*)((const u16*)wih + (long)kidx*1536*768);
  const void* whhd = mode ? (const void*)((const float*)whh + (long)kidx*1536*384)
                          : (const void*)((const u16*)whh + (long)kidx*1536*384);
  short8 wb[36];                               // K=1152 = 36 k-steps of 32
  {
    long row = (long)g*384 + j0 + hl;
#pragma unroll
    for (int ks=0;ks<24;ks++) wb[ks]    = ldw8(wihd, row*768 + ks*32 + q*8, mode);
#pragma unroll
    for (int ks=0;ks<12;ks++) wb[24+ks] = ldw8(whhd, row*384 + ks*32 + q*8, mode);
  }
  float bias[4];
#pragma unroll
  for (int r=0;r<4;r++) bias[r] = lds1(blstm, (long)kidx*1536 + r*384 + j0 + q, mode);
  float cst[4] = {0.f,0.f,0.f,0.f};

  for (int t=0;t<200;++t){
    if (w==0){
      if (layer==0){
        // own-dir l0 peers completed step t-1 (time slot t ready)
        int fi  = (lane<24) ? (d*24+lane)*32 : 0;
        int tgt = (lane<24) ? t : 0;
        while (1){
          int v = __hip_atomic_load(&flags[fi], __ATOMIC_RELAXED, __HIP_MEMORY_SCOPE_AGENT);
          if (__all(v >= tgt)) break;
          __builtin_amdgcn_s_sleep(1);
        }
        if (t >= R0S){                         // ring back-pressure vs layer-1
          fi  = (lane<48) ? (48+lane)*32 : 0;
          tgt = (lane<48) ? (t - (R0S-1)) : 0;
          while (1){
            int v = __hip_atomic_load(&flags[fi], __ATOMIC_RELAXED, __HIP_MEMORY_SCOPE_AGENT);
            if (__all(v >= tgt)) break;
            __builtin_amdgcn_s_sleep(1);
          }
        }
      } else {
        // all layer-0 done step t (l0 time t+1 ready) ...
        int fi  = (lane<48) ? lane*32 : 0;
        int tgt = (lane<48) ? (t+1) : 0;
        while (1){
          int v = __hip_atomic_load(&flags[fi], __ATOMIC_RELAXED, __HIP_MEMORY_SCOPE_AGENT);
          if (__all(v >= tgt)) break;
          __builtin_amdgcn_s_sleep(1);
        }
        // ... and own-dir layer-1 peers done step t-1 (l1 time t ready)
        fi  = (lane<24) ? (48 + d*24 + lane)*32 : 0;
        tgt = (lane<24) ? t : 0;
        while (1){
          int v = __hip_atomic_load(&flags[fi], __ATOMIC_RELAXED, __HIP_MEMORY_SCOPE_AGENT);
          if (__all(v >= tgt)) break;
          __builtin_amdgcn_s_sleep(1);
        }
      }
      __threadfence();                         // acquire
    }
    if (layer==0 && tid < 64) stok[tid] = ctx[tid*200 + t];

    f32x4 acc[4];
#pragma unroll
    for (int Nt=0;Nt<4;Nt++) acc[Nt] = (f32x4){0.f,0.f,0.f,0.f};

    for (int c=0;c<3;c++){                     // K chunks of 384
      __syncthreads();
#pragma unroll
      for (int r=0;r<12;r++){                  // stage 64x384 bf16 into lact
        int flat = r*4096 + tid*16;            // byte offset within 64x768B
        int rowi = flat/768, off = (flat%768)>>1;
        if (layer==0){
          if (c<2) stage8(&lact[rowi*392+off], emb, (long)stok[rowi]*768 + c*384 + off, mode);
          else *(u16x8*)&lact[rowi*392+off] =
            *(const u16x8*)(l0r + ((t&7)*L0SLOT + rowi*768 + d*384) + off);
        } else {
          const u16* s = (c<2)
            ? (l0r + (((t+1)&7)*L0SLOT + rowi*768 + c*384) + off)
            : (l1r + ((t&1)*L0SLOT + rowi*768 + d*384) + off);
          *(u16x8*)&lact[rowi*392+off] = *(const u16x8*)s;
        }
      }
      __syncthreads();
#pragma unroll
      for (int ks=0;ks<12;ks++){
        short8 bf[4];
#pragma unroll
        for (int Nt=0;Nt<4;Nt++)
          bf[Nt] = *(const short8*)&lact[(Nt*16 + m15)*392 + ks*32 + q*8];
#pragma unroll
        for (int Nt=0;Nt<4;Nt++)
          acc[Nt] = MFMA16x16x32(wb[c*12+ks], bf[Nt], acc[Nt], 0,0,0);
      }
    }
#pragma unroll
    for (int Nt=0;Nt<4;Nt++){
      float gi = sigf(acc[Nt][0] + bias[0]);
      float gf = sigf(acc[Nt][1] + bias[1]);
      float gz = tanh_(acc[Nt][2] + bias[2]);
      float go = sigf(acc[Nt][3] + bias[3]);
      float c2 = gf*cst[Nt] + gi*gz;           // c stays fp32 in registers
      cst[Nt] = c2;
      float hn = go*tanh_(c2);
      hstage[(Nt*16 + m15)*16 + (w*4 + q)] = f2bf(hn);
      if (layer==1 && spos[Nt*16 + m15] == t)  // target = reps[pos[b]], FP32
        out[256 + (Nt*16 + m15)*768 + d*384 + slot*16 + w*4 + q] = hn;
    }
    __syncthreads();
    {                                          // coalesced h write: 64x16 bf16
      int b = tid >> 2, off = (tid & 3)*4;
      unsigned long long vv = *(const unsigned long long*)&hstage[b*16 + off];
      u16* dst = layer
        ? (l1r + (((t+1)&1)*L0SLOT + b*768 + d*384 + slot*16) + off)
        : (l0r + (((t+1)&7)*L0SLOT + b*768 + d*384 + slot*16) + off);
      *(unsigned long long*)dst = vv;
    }
    __syncthreads();
    if (tid==0){
      __threadfence();                         // release
      __hip_atomic_store(&flags[wg*32], t+1, __ATOMIC_RELAXED, __HIP_MEMORY_SCOPE_AGENT);
    }
  }
}

// ---- K4: classifier head over the fp32 target rows already in out ----------
__global__ __launch_bounds__(64) void k4_out(
    const void* __restrict__ wcls, const void* __restrict__ bcls,
    const int* __restrict__ wsmode, float* __restrict__ out){
  const int mode = wsmode[0];
  int b = blockIdx.x, lane = threadIdx.x;
  float a0=0.f, a1=0.f;
#pragma unroll
  for (int ch=0; ch<12; ++ch){
    int e = ch*64 + lane;
    float xv = out[256 + b*768 + e];
    a0 += xv * lds1(wcls, e, mode);
    a1 += xv * lds1(wcls, 768 + e, mode);
  }
#pragma unroll
  for (int off=32; off>0; off>>=1){
    a0 += __shfl_down(a0, off);
    a1 += __shfl_down(a1, off);
  }
  if (lane==0){
    float l0v = a0 + lds1(bcls, 0, mode);
    float l1v = a1 + lds1(bcls, 1, mode);
    out[b*2+0]     = l0v;                      // logits, fp32
    out[b*2+1]     = l1v;
    out[128+b*2+0] = sigf(l0v);                // probs, fp32
    out[128+b*2+1] = sigf(l1v);
  }
}

extern "C" void kernel_launch(void* const* d_in, const int* in_sizes, int n_in,
                              void* d_out, int out_size, void* d_ws, size_t ws_size,
                              hipStream_t stream){
  (void)in_sizes; (void)n_in; (void)out_size; (void)ws_size;
  const int* ctx  = (const int*)d_in[0];
  const int* pos  = (const int*)d_in[1];
  const void* emb = d_in[2];
  const void* wih = d_in[3];
  const void* whh = d_in[4];
  const void* blst= d_in[5];
  const void* wcls= d_in[6];
  const void* bcls= d_in[7];
  char* ws = (char*)d_ws;
  int* wsmode = (int*)ws;
  int* flags  = (int*)(ws + WS_FLAGS_OFF);
  u16* l0r    = (u16*)(ws + WS_L0_OFF);        // 8 slots x 96 KB
  u16* l1r    = (u16*)(ws + WS_L1_OFF);        // 2 slots x 96 KB
  float* out  = (float*)d_out;
  hipLaunchKernelGGL(kdet, dim3(1), dim3(256), 0, stream,
                     (const unsigned int*)emb, wsmode);
  hipLaunchKernelGGL(k0_init, dim3(96), dim3(256), 0, stream,
                     (unsigned int*)l0r, (unsigned int*)l1r, flags);
  hipLaunchKernelGGL(k3_lstm, dim3(96), dim3(256), 0, stream,
                     wih, whh, blst, emb, ctx, pos, l0r, l1r, flags, wsmode, out);
  hipLaunchKernelGGL(k4_out, dim3(64), dim3(64), 0, stream, wcls, bcls, wsmode, out);
}

// Round 6
// 4191.496 us; speedup vs baseline: 1.2581x; 1.2581x over previous
//
#include <hip/hip_runtime.h>
#include <stdint.h>

typedef unsigned short u16;
typedef unsigned long long u64;
typedef short short8 __attribute__((ext_vector_type(8)));
typedef unsigned short u16x8 __attribute__((ext_vector_type(8)));
typedef float f32x4 __attribute__((ext_vector_type(4)));

#define MFMA16x16x32 __builtin_amdgcn_mfma_f32_16x16x32_bf16

#define L0SLOT (64*768)          // u16 elements per time-slot (64 batch x 768)
#define R0S 16                   // l0 ring depth (slots) — lets layer-0 run ahead
// ws layout (bytes): [0,4) mode | [256,12544) flags 96x32 ints | l0 ring | l1 ring
#define WS_FLAGS_OFF 256
#define WS_L0_OFF    12544
#define WS_L1_OFF    (12544 + R0S*L0SLOT*2)      // l1 ring: 2 slots

static __device__ __forceinline__ float bf2f(u16 u){
  union{unsigned int i; float f;} v; v.i=((unsigned int)u)<<16; return v.f;
}
static __device__ __forceinline__ u16 f2bf(float f){
  union{float f; unsigned int i;} v; v.f=f;
  return (u16)((v.i + 0x7fffu + ((v.i>>16)&1u))>>16);   // RNE
}
static __device__ __forceinline__ float sigf(float x){
  return __fdividef(1.f, 1.f + __expf(-x));
}
static __device__ __forceinline__ float tanh_(float x){
  return 1.f - __fdividef(2.f, __expf(2.f*x) + 1.f);
}
// coherent (agent-scope, sc-flagged) 8B load/store: per-access coherence, no
// bulk cache fences needed anywhere in the step loop.
static __device__ __forceinline__ u64 cohld(const u16* p){
  return __hip_atomic_load((const u64*)p, __ATOMIC_RELAXED, __HIP_MEMORY_SCOPE_AGENT);
}
static __device__ __forceinline__ void cohst(u16* p, u64 v){
  __hip_atomic_store((u64*)p, v, __ATOMIC_RELAXED, __HIP_MEMORY_SCOPE_AGENT);
}
// mode: 1 = tensor is fp32 (convert on load), 0 = tensor is bf16
static __device__ __forceinline__ void stage8(u16* dst, const void* base, long e, int mode){
  if (mode==0){
    *(u16x8*)dst = *(const u16x8*)((const u16*)base + e);
  } else {
    const float* p = (const float*)base + e;
    float4 a = *(const float4*)p, b = *(const float4*)(p+4);
    u16x8 v; v[0]=f2bf(a.x); v[1]=f2bf(a.y); v[2]=f2bf(a.z); v[3]=f2bf(a.w);
    v[4]=f2bf(b.x); v[5]=f2bf(b.y); v[6]=f2bf(b.z); v[7]=f2bf(b.w);
    *(u16x8*)dst = v;
  }
}
static __device__ __forceinline__ short8 ldw8(const void* base, long e, int mode){
  if (mode==0) return *(const short8*)((const u16*)base + e);
  const float* p = (const float*)base + e;
  float4 a = *(const float4*)p, b = *(const float4*)(p+4);
  short8 r; r[0]=(short)f2bf(a.x); r[1]=(short)f2bf(a.y); r[2]=(short)f2bf(a.z); r[3]=(short)f2bf(a.w);
  r[4]=(short)f2bf(b.x); r[5]=(short)f2bf(b.y); r[6]=(short)f2bf(b.z); r[7]=(short)f2bf(b.w);
  return r;
}
static __device__ __forceinline__ float lds1(const void* base, long e, int mode){
  return mode ? ((const float*)base)[e] : bf2f(((const u16*)base)[e]);
}

// ---- Kd: dtype detection on raw W_emb words (kept as cheap insurance). -----
__global__ void kdet(const unsigned int* __restrict__ w, int* wsmode){
  __shared__ int sh[256];
  int c = 0;
  for (int i=threadIdx.x; i<4096; i+=256){
    unsigned int x = w[i] & 0xFFFFu;
    if (((x>>7)&0xFFu) >= 0x80u) c++;
  }
  sh[threadIdx.x]=c; __syncthreads();
  for (int s=128;s>0;s>>=1){
    if (threadIdx.x<s) sh[threadIdx.x]+=sh[threadIdx.x+s];
    __syncthreads();
  }
  if (threadIdx.x==0) wsmode[0] = (sh[0] > 256) ? 1 : 0;
}

// ---- K0: zero ring slot-0s + flags (ws re-poisoned 0xAA before every call) --
__global__ void k0_init(unsigned int* l0, unsigned int* l1, int* flags){
  int i = blockIdx.x*256 + threadIdx.x;       // 24576 threads
  l0[i] = 0u;                                 // l0 ring slot 0 (24576 dwords)
  l1[i] = 0u; l1[i + 24576] = 0u;             // both l1 slots
  if (i < 3072) flags[i] = 0;                 // 96 flags, 128B-strided
}

// ---- K3: persistent 4-chain LSTM, unified K=1152 cells, ring buffers -------
// 96 WGs x 256. wg 0..47: layer-0 (d=wg/24, slot=wg%24); wg 48..95: layer-1.
// gates[16 x 64] = W[16 gate-rows x 1152] @ act[1152 x 64],
// act = [input(768) | own-h(384)]. Weights register-resident as MFMA A-frags;
// c stays fp32 in registers for all 200 steps. Cross-WG h rings + flags use
// per-access agent-scope coherence (no __threadfence => no L2 inv/wb storms).
// Release ordering: __syncthreads() drains vmcnt(0) before the flag store.
__global__ __launch_bounds__(256,1) void k3_lstm(
    const void* __restrict__ wih, const void* __restrict__ whh,
    const void* __restrict__ blstm, const void* __restrict__ emb,
    const int* __restrict__ ctx, const int* __restrict__ pos,
    u16* __restrict__ l0r, u16* __restrict__ l1r, int* flags,
    const int* __restrict__ wsmode, float* __restrict__ out){
  __shared__ __align__(16) u16 lact[64*392];   // act chunk [64 batch][384+8 pad]
  __shared__ __align__(16) u16 hstage[64*16];
  __shared__ int stok[64];
  __shared__ int spos[64];
  const int mode = wsmode[0];
  const int tid = threadIdx.x, lane = tid & 63, w = tid >> 6;
  const int m15 = lane & 15, q = lane >> 4;
  const int wg = blockIdx.x;
  const int layer = (wg >= 48) ? 1 : 0;
  const int x = wg - layer*48;
  const int d = x / 24, slot = x % 24;
  const int kidx = 2*layer + d;
  const int j0 = slot*16 + w*4;                // this wave's 4 h-dims
  const int g = m15 & 3, hl = m15 >> 2;        // A-row m15 -> (gate, hdim)

  if (tid < 64) spos[tid] = pos[tid];
  const void* wihd = mode ? (const void*)((const float*)wih + (long)kidx*1536*768)
                          : (const void*)((const u16*)wih + (long)kidx*1536*768);
  const void* whhd = mode ? (const void*)((const float*)whh + (long)kidx*1536*384)
                          : (const void*)((const u16*)whh + (long)kidx*1536*384);
  short8 wb[36];                               // K=1152 = 36 k-steps of 32
  {
    long row = (long)g*384 + j0 + hl;
#pragma unroll
    for (int ks=0;ks<24;ks++) wb[ks]    = ldw8(wihd, row*768 + ks*32 + q*8, mode);
#pragma unroll
    for (int ks=0;ks<12;ks++) wb[24+ks] = ldw8(whhd, row*384 + ks*32 + q*8, mode);
  }
  float bias[4];
#pragma unroll
  for (int r=0;r<4;r++) bias[r] = lds1(blstm, (long)kidx*1536 + r*384 + j0 + q, mode);
  float cst[4] = {0.f,0.f,0.f,0.f};

  for (int t=0;t<200;++t){
    if (w==0){
      if (layer==0){
        // own-dir l0 peers completed step t-1 (time slot t ready)
        int fi  = (lane<24) ? (d*24+lane)*32 : 0;
        int tgt = (lane<24) ? t : 0;
        while (1){
          int v = __hip_atomic_load(&flags[fi], __ATOMIC_RELAXED, __HIP_MEMORY_SCOPE_AGENT);
          if (__all(v >= tgt)) break;
          __builtin_amdgcn_s_sleep(1);
        }
        if (t >= R0S){                         // ring back-pressure vs layer-1
          fi  = (lane<48) ? (48+lane)*32 : 0;
          tgt = (lane<48) ? (t - (R0S-1)) : 0;
          while (1){
            int v = __hip_atomic_load(&flags[fi], __ATOMIC_RELAXED, __HIP_MEMORY_SCOPE_AGENT);
            if (__all(v >= tgt)) break;
            __builtin_amdgcn_s_sleep(1);
          }
        }
      } else {
        // all layer-0 done step t (l0 time t+1 ready; usually pre-satisfied) ...
        int fi  = (lane<48) ? lane*32 : 0;
        int tgt = (lane<48) ? (t+1) : 0;
        while (1){
          int v = __hip_atomic_load(&flags[fi], __ATOMIC_RELAXED, __HIP_MEMORY_SCOPE_AGENT);
          if (__all(v >= tgt)) break;
          __builtin_amdgcn_s_sleep(1);
        }
        // ... and own-dir layer-1 peers done step t-1 (l1 time t ready)
        fi  = (lane<24) ? (48 + d*24 + lane)*32 : 0;
        tgt = (lane<24) ? t : 0;
        while (1){
          int v = __hip_atomic_load(&flags[fi], __ATOMIC_RELAXED, __HIP_MEMORY_SCOPE_AGENT);
          if (__all(v >= tgt)) break;
          __builtin_amdgcn_s_sleep(1);
        }
      }
    }
    if (layer==0 && tid < 64) stok[tid] = ctx[tid*200 + t];

    f32x4 acc[4];
#pragma unroll
    for (int Nt=0;Nt<4;Nt++) acc[Nt] = (f32x4){0.f,0.f,0.f,0.f};

    for (int c=0;c<3;c++){                     // K chunks of 384
      __syncthreads();
      if (layer==0 && c<2){
#pragma unroll
        for (int r=0;r<12;r++){                // emb: read-only, cached loads
          int flat = r*4096 + tid*16;
          int rowi = flat/768, off = (flat%768)>>1;
          stage8(&lact[rowi*392+off], emb, (long)stok[rowi]*768 + c*384 + off, mode);
        }
      } else {
#pragma unroll
        for (int r=0;r<12;r++){                // ring: coherent 8B loads
          int flat = r*4096 + tid*16;
          int rowi = flat/768, off = (flat%768)>>1;
          const u16* s;
          if (layer==0)
            s = l0r + ((t&(R0S-1))*L0SLOT + rowi*768 + d*384) + off;
          else
            s = (c<2) ? (l0r + (((t+1)&(R0S-1))*L0SLOT + rowi*768 + c*384) + off)
                      : (l1r + ((t&1)*L0SLOT + rowi*768 + d*384) + off);
          u64 v0 = cohld(s), v1 = cohld(s+4);
          u16* dl = &lact[rowi*392+off];
          *(u64*)dl = v0; *(u64*)(dl+4) = v1;
        }
      }
      __syncthreads();
#pragma unroll
      for (int ks=0;ks<12;ks++){
        short8 bf[4];
#pragma unroll
        for (int Nt=0;Nt<4;Nt++)
          bf[Nt] = *(const short8*)&lact[(Nt*16 + m15)*392 + ks*32 + q*8];
#pragma unroll
        for (int Nt=0;Nt<4;Nt++)
          acc[Nt] = MFMA16x16x32(wb[c*12+ks], bf[Nt], acc[Nt], 0,0,0);
      }
    }
#pragma unroll
    for (int Nt=0;Nt<4;Nt++){
      float gi = sigf(acc[Nt][0] + bias[0]);
      float gf = sigf(acc[Nt][1] + bias[1]);
      float gz = tanh_(acc[Nt][2] + bias[2]);
      float go = sigf(acc[Nt][3] + bias[3]);
      float c2 = gf*cst[Nt] + gi*gz;           // c stays fp32 in registers
      cst[Nt] = c2;
      float hn = go*tanh_(c2);
      hstage[(Nt*16 + m15)*16 + (w*4 + q)] = f2bf(hn);
      if (layer==1 && spos[Nt*16 + m15] == t)  // target = reps[pos[b]], FP32
        out[256 + (Nt*16 + m15)*768 + d*384 + slot*16 + w*4 + q] = hn;
    }
    __syncthreads();
    {                                          // coherent h write: 64x16 bf16
      int b = tid >> 2, off = (tid & 3)*4;
      u64 vv = *(const u64*)&hstage[b*16 + off];
      u16* dst = layer
        ? (l1r + (((t+1)&1)*L0SLOT + b*768 + d*384 + slot*16) + off)
        : (l0r + (((t+1)&(R0S-1))*L0SLOT + b*768 + d*384 + slot*16) + off);
      cohst(dst, vv);
    }
    __syncthreads();                           // drains vmcnt(0): release order
    if (tid==0)
      __hip_atomic_store(&flags[wg*32], t+1, __ATOMIC_RELAXED, __HIP_MEMORY_SCOPE_AGENT);
  }
}

// ---- K4: classifier head over the fp32 target rows already in out ----------
__global__ __launch_bounds__(64) void k4_out(
    const void* __restrict__ wcls, const void* __restrict__ bcls,
    const int* __restrict__ wsmode, float* __restrict__ out){
  const int mode = wsmode[0];
  int b = blockIdx.x, lane = threadIdx.x;
  float a0=0.f, a1=0.f;
#pragma unroll
  for (int ch=0; ch<12; ++ch){
    int e = ch*64 + lane;
    float xv = out[256 + b*768 + e];
    a0 += xv * lds1(wcls, e, mode);
    a1 += xv * lds1(wcls, 768 + e, mode);
  }
#pragma unroll
  for (int off=32; off>0; off>>=1){
    a0 += __shfl_down(a0, off);
    a1 += __shfl_down(a1, off);
  }
  if (lane==0){
    float l0v = a0 + lds1(bcls, 0, mode);
    float l1v = a1 + lds1(bcls, 1, mode);
    out[b*2+0]     = l0v;                      // logits, fp32
    out[b*2+1]     = l1v;
    out[128+b*2+0] = sigf(l0v);                // probs, fp32
    out[128+b*2+1] = sigf(l1v);
  }
}

extern "C" void kernel_launch(void* const* d_in, const int* in_sizes, int n_in,
                              void* d_out, int out_size, void* d_ws, size_t ws_size,
                              hipStream_t stream){
  (void)in_sizes; (void)n_in; (void)out_size; (void)ws_size;
  const int* ctx  = (const int*)d_in[0];
  const int* pos  = (const int*)d_in[1];
  const void* emb = d_in[2];
  const void* wih = d_in[3];
  const void* whh = d_in[4];
  const void* blst= d_in[5];
  const void* wcls= d_in[6];
  const void* bcls= d_in[7];
  char* ws = (char*)d_ws;
  int* wsmode = (int*)ws;
  int* flags  = (int*)(ws + WS_FLAGS_OFF);
  u16* l0r    = (u16*)(ws + WS_L0_OFF);        // 16 slots x 96 KB
  u16* l1r    = (u16*)(ws + WS_L1_OFF);        // 2 slots x 96 KB
  float* out  = (float*)d_out;
  hipLaunchKernelGGL(kdet, dim3(1), dim3(256), 0, stream,
                     (const unsigned int*)emb, wsmode);
  hipLaunchKernelGGL(k0_init, dim3(96), dim3(256), 0, stream,
                     (unsigned int*)l0r, (unsigned int*)l1r, flags);
  hipLaunchKernelGGL(k3_lstm, dim3(96), dim3(256), 0, stream,
                     wih, whh, blst, emb, ctx, pos, l0r, l1r, flags, wsmode, out);
  hipLaunchKernelGGL(k4_out, dim3(64), dim3(64), 0, stream, wcls, bcls, wsmode, out);
}

// Round 7
// 3429.251 us; speedup vs baseline: 1.5378x; 1.2223x over previous
//
#include <hip/hip_runtime.h>
#include <stdint.h>

typedef unsigned short u16;
typedef unsigned long long u64;
typedef short short8 __attribute__((ext_vector_type(8)));
typedef unsigned short u16x4 __attribute__((ext_vector_type(4)));
typedef unsigned short u16x8 __attribute__((ext_vector_type(8)));
typedef float f32x4 __attribute__((ext_vector_type(4)));

#define MFMA16x16x32 __builtin_amdgcn_mfma_f32_16x16x32_bf16

#define XPR    24        // Xp ring depth (steps)
#define L0HR   64        // l0 h-history ring depth (steps)
#define TSLOT  49152L    // u16 per h time-slot (64 x 768)
#define XPSLOT 98304L    // u16 per Xp time-slot (64 x 1536, gate-major per hdim)

// ws byte layout: mode | flags(80x128B) | Xp rings(4 kidx) | l0h ring | l1 ring
#define WS_FLAGS 256L
#define WS_XP    16384L
#define WS_L0H   (WS_XP + 4L*XPR*XPSLOT*2)      // +18,874,368
#define WS_L1R   (WS_L0H + L0HR*TSLOT*2)        // +6,291,456 (total ~25.4 MB)

static __device__ __forceinline__ float bf2f(u16 u){
  union{unsigned int i; float f;} v; v.i=((unsigned int)u)<<16; return v.f;
}
static __device__ __forceinline__ u16 f2bf(float f){
  union{float f; unsigned int i;} v; v.f=f;
  return (u16)((v.i + 0x7fffu + ((v.i>>16)&1u))>>16);   // RNE
}
static __device__ __forceinline__ float sigf(float x){
  return __fdividef(1.f, 1.f + __expf(-x));
}
static __device__ __forceinline__ float tanh_(float x){
  return 1.f - __fdividef(2.f, __expf(2.f*x) + 1.f);
}
// coherent (agent-scope, cache-bypassing) accesses for cross-WG data
static __device__ __forceinline__ u64 cohld(const u16* p){
  return __hip_atomic_load((const u64*)p, __ATOMIC_RELAXED, __HIP_MEMORY_SCOPE_AGENT);
}
static __device__ __forceinline__ void cohst(u16* p, u64 v){
  __hip_atomic_store((u64*)p, v, __ATOMIC_RELAXED, __HIP_MEMORY_SCOPE_AGENT);
}
static __device__ __forceinline__ int fld(const int* flags, int fi){
  return __hip_atomic_load(&flags[fi*32], __ATOMIC_RELAXED, __HIP_MEMORY_SCOPE_AGENT);
}
static __device__ __forceinline__ void fst(int* flags, int fi, int v){
  __hip_atomic_store(&flags[fi*32], v, __ATOMIC_RELAXED, __HIP_MEMORY_SCOPE_AGENT);
}
// mode: 1 = tensor is fp32 (convert on load), 0 = tensor is bf16
static __device__ __forceinline__ void stage8(u16* dst, const void* base, long e, int mode){
  if (mode==0){
    *(u16x8*)dst = *(const u16x8*)((const u16*)base + e);
  } else {
    const float* p = (const float*)base + e;
    float4 a = *(const float4*)p, b = *(const float4*)(p+4);
    u16x8 v; v[0]=f2bf(a.x); v[1]=f2bf(a.y); v[2]=f2bf(a.z); v[3]=f2bf(a.w);
    v[4]=f2bf(b.x); v[5]=f2bf(b.y); v[6]=f2bf(b.z); v[7]=f2bf(b.w);
    *(u16x8*)dst = v;
  }
}
static __device__ __forceinline__ short8 ldw8(const void* base, long e, int mode){
  if (mode==0) return *(const short8*)((const u16*)base + e);
  const float* p = (const float*)base + e;
  float4 a = *(const float4*)p, b = *(const float4*)(p+4);
  short8 r; r[0]=(short)f2bf(a.x); r[1]=(short)f2bf(a.y); r[2]=(short)f2bf(a.z); r[3]=(short)f2bf(a.w);
  r[4]=(short)f2bf(b.x); r[5]=(short)f2bf(b.y); r[6]=(short)f2bf(b.z); r[7]=(short)f2bf(b.w);
  return r;
}
static __device__ __forceinline__ float lds1(const void* base, long e, int mode){
  return mode ? ((const float*)base)[e] : bf2f(((const u16*)base)[e]);
}

// ---- Kd: dtype detection on raw W_emb words (fp32 vs bf16) -----------------
__global__ void kdet(const unsigned int* __restrict__ w, int* wsmode){
  __shared__ int sh[256];
  int c = 0;
  for (int i=threadIdx.x; i<4096; i+=256){
    unsigned int x = w[i] & 0xFFFFu;
    if (((x>>7)&0xFFu) >= 0x80u) c++;
  }
  sh[threadIdx.x]=c; __syncthreads();
  for (int s=128;s>0;s>>=1){
    if (threadIdx.x<s) sh[threadIdx.x]+=sh[threadIdx.x+s];
    __syncthreads();
  }
  if (threadIdx.x==0) wsmode[0] = (sh[0] > 256) ? 1 : 0;
}

// ---- K0: zero h ring slot-0s + flags ---------------------------------------
__global__ void k0_init(unsigned int* l0h, unsigned int* l1r, int* flags){
  int i = blockIdx.x*256 + threadIdx.x;       // 96*256 = 24576
  l0h[i] = 0u;                                // l0h ring slot 0
  l1r[i] = 0u; l1r[i + 24576] = 0u;           // both l1 slots
  if (i < 2560) flags[i] = 0;                 // 80 flags, 128B-strided
}

// ---- K3: 80 persistent WGs ---------------------------------------------------
// wg 0..31  : chain WGs. layer=wg>>4, d=(wg>>3)&1, slot=wg&7. 48 hdims each.
//             Per step: gates = Xp_k[t] (precomputed, bias folded) + h(t-1)@Whh^T
//             (K=384, Whh register-resident, 3 Mtiles x 12 ksteps per wave).
// wg 32..55 : l0-helpers (kidx=d=(wg-32)/12, 12 WGs x 32 hdims): Xp0[t] =
//             emb[ctx[:,t]] @ Wih_d^T + b_d  (cached emb loads, K=768).
// wg 56..79 : l1-helpers (kidx=2+d): Xp1[t] = l0h(t+1) @ Wih^T + b (coherent).
// Xp layout per kidx: [t%XPR][b][hdim*4+gate] bf16 => chains acc-init with one
// 8B coherent load per (Mt,Nt). Flags: monotonic per-WG step counters;
// release order = __syncthreads() (vmcnt drain) before flag store (verified R5/6).
__global__ __launch_bounds__(256,1) void k3_lstm(
    const void* __restrict__ wih, const void* __restrict__ whh,
    const void* __restrict__ blstm, const void* __restrict__ emb,
    const int* __restrict__ ctx, const int* __restrict__ pos,
    u16* __restrict__ xp, u16* __restrict__ l0h, u16* __restrict__ l1r,
    int* flags, const int* __restrict__ wsmode, float* __restrict__ out){
  __shared__ __align__(16) u16 lact[64*776];   // helpers: stride 776; chains: 392
  __shared__ __align__(16) u16 hstage[64*48];
  __shared__ int stok[64];
  __shared__ int spos[64];
  const int mode = wsmode[0];
  const int tid = threadIdx.x, lane = tid & 63, w = tid >> 6;
  const int m15 = lane & 15, q = lane >> 4;
  const int g = m15 & 3, hl = m15 >> 2;        // A-row m15 -> (gate, hdim) [verified]
  const int wg = blockIdx.x;

  if (wg < 32){
    // ================= chain WG =================
    const int layer = wg >> 4, d = (wg >> 3) & 1, slot = wg & 7;
    const int kidx = 2*layer + d;
    const int j0 = slot*48 + w*12;             // wave covers 12 hdims (3 Mtiles)
    const void* whhd = mode ? (const void*)((const float*)whh + (long)kidx*1536*384)
                            : (const void*)((const u16*)whh + (long)kidx*1536*384);
    short8 wa[3][12];
#pragma unroll
    for (int Mt=0;Mt<3;Mt++){
      long row = (long)g*384 + j0 + Mt*4 + hl;
#pragma unroll
      for (int ks=0;ks<12;ks++)
        wa[Mt][ks] = ldw8(whhd, row*384 + ks*32 + q*8, mode);
    }
    if (tid < 64) spos[tid] = pos[tid];
    u16* xpk  = xp + (long)kidx*XPR*XPSLOT;
    u16* hbuf = layer ? l1r : l0h;
    const int selfF = layer*16 + d*8 + slot;
    const int helpB = layer ? 56 + d*12 : 32 + d*12;
    float cst[3][4];
#pragma unroll
    for(int i=0;i<3;i++)
#pragma unroll
      for(int j=0;j<4;j++) cst[i][j]=0.f;

    for (int t=0;t<200;++t){
      if (w==0){
        int fi, tgt;
        if (lane < 12){ fi = helpB + lane; tgt = t+1; }        // Xp[t] ready
        else if (lane < 20){ fi = layer*16 + d*8 + (lane-12); tgt = t; } // peers
        else { fi = 0; tgt = 0; }
        while (1){ int v = fld(flags, fi); if (__all(v >= tgt)) break;
                   __builtin_amdgcn_s_sleep(1); }
        if (layer==0 && (t & 15) == 0){        // l0h ring space vs l1-helpers
          fi  = (lane < 24) ? 56 + lane : 0;
          tgt = (lane < 24) ? t - 48 : 0;
          while (1){ int v = fld(flags, fi); if (__all(v >= tgt)) break;
                     __builtin_amdgcn_s_sleep(1); }
        }
      }
      __syncthreads();                         // gate all waves on the poll
      // acc-init: Xp coherent loads (issued early to overlap h staging)
      u64 xr[3][4];
      const long xb = (long)(t % XPR)*XPSLOT;
#pragma unroll
      for (int Mt=0;Mt<3;Mt++)
#pragma unroll
        for (int Nt=0;Nt<4;Nt++)
          xr[Mt][Nt] = cohld(xpk + xb + (long)(Nt*16+m15)*1536 + (j0+Mt*4+q)*4);
      // stage own-dir h(t): 64x384 bf16, coherent
      {
        const long hb = layer ? (long)(t & 1)*TSLOT : (long)(t % L0HR)*TSLOT;
#pragma unroll
        for (int r=0;r<12;r++){
          int flat = r*4096 + tid*16;          // byte offset within 64x768B
          int rowi = flat/768, off = (flat%768)>>1;
          const u16* s = hbuf + hb + (long)rowi*768 + d*384 + off;
          u64 v0 = cohld(s), v1 = cohld(s+4);
          *(u64*)&lact[rowi*392+off] = v0; *(u64*)&lact[rowi*392+off+4] = v1;
        }
      }
      __syncthreads();
      f32x4 acc[3][4];
#pragma unroll
      for (int Mt=0;Mt<3;Mt++)
#pragma unroll
        for (int Nt=0;Nt<4;Nt++){
          union{u64 v; u16x4 h;} u; u.v = xr[Mt][Nt];
          acc[Mt][Nt] = (f32x4){ bf2f(u.h[0]), bf2f(u.h[1]), bf2f(u.h[2]), bf2f(u.h[3]) };
        }
#pragma unroll
      for (int ks=0;ks<12;ks++){
        short8 bf[4];
#pragma unroll
        for (int Nt=0;Nt<4;Nt++)
          bf[Nt] = *(const short8*)&lact[(Nt*16 + m15)*392 + ks*32 + q*8];
#pragma unroll
        for (int Mt=0;Mt<3;Mt++)
#pragma unroll
          for (int Nt=0;Nt<4;Nt++)
            acc[Mt][Nt] = MFMA16x16x32(wa[Mt][ks], bf[Nt], acc[Mt][Nt], 0,0,0);
      }
#pragma unroll
      for (int Mt=0;Mt<3;Mt++)
#pragma unroll
        for (int Nt=0;Nt<4;Nt++){
          float gi = sigf(acc[Mt][Nt][0]);     // bias already folded into Xp
          float gf = sigf(acc[Mt][Nt][1]);
          float gz = tanh_(acc[Mt][Nt][2]);
          float go = sigf(acc[Mt][Nt][3]);
          float c2 = gf*cst[Mt][Nt] + gi*gz;   // c stays fp32 in registers
          cst[Mt][Nt] = c2;
          float hn = go*tanh_(c2);
          hstage[(Nt*16 + m15)*48 + (w*12 + Mt*4 + q)] = f2bf(hn);
          if (layer==1 && spos[Nt*16 + m15] == t)   // target rows, fp32
            out[256 + (Nt*16 + m15)*768 + d*384 + slot*48 + w*12 + Mt*4 + q] = hn;
        }
      __syncthreads();
      {                                        // coherent h write: 64x48 bf16
        const long ob = layer ? (long)((t+1) & 1)*TSLOT : (long)((t+1) % L0HR)*TSLOT;
#pragma unroll
        for (int s2=0;s2<3;s2++){
          int flat = tid*24 + s2*8;
          int b = flat/96, off = (flat%96)>>1;
          cohst(hbuf + ob + (long)b*768 + d*384 + slot*48 + off,
                *(const u64*)&hstage[b*48 + off]);
        }
      }
      __syncthreads();                         // vmcnt drain: release order
      if (tid==0) fst(flags, selfF, t+1);
    }
  } else {
    // ================= helper WG (Xp producer GEMM) =================
    const int isl1 = (wg >= 56);
    const int hx = wg - (isl1 ? 56 : 32);
    const int d = hx / 12, s12 = hx % 12;
    const int kidx = isl1 ? 2 + d : d;
    const int j0h = s12*32 + w*8;              // wave covers 8 hdims (2 Mtiles)
    const void* wihd = mode ? (const void*)((const float*)wih + (long)kidx*1536*768)
                            : (const void*)((const u16*)wih + (long)kidx*1536*768);
    short8 wbh[2][24];
#pragma unroll
    for (int Mt=0;Mt<2;Mt++){
      long row = (long)g*384 + j0h + Mt*4 + hl;
#pragma unroll
      for (int ks=0;ks<24;ks++)
        wbh[Mt][ks] = ldw8(wihd, row*768 + ks*32 + q*8, mode);
    }
    float bias[2][4];
#pragma unroll
    for (int Mt=0;Mt<2;Mt++)
#pragma unroll
      for (int r=0;r<4;r++)
        bias[Mt][r] = lds1(blstm, (long)kidx*1536 + r*384 + j0h + Mt*4 + q, mode);
    u16* xpk = xp + (long)kidx*XPR*XPSLOT;
    const int selfF = (isl1 ? 56 : 32) + d*12 + s12;

    for (int t=0;t<200;++t){
      if (w==0){
        int fi, tgt;
        if (!isl1){                            // Xp0 ring space vs l0-chain dir d
          fi  = (lane < 8) ? d*8 + lane : 0;
          tgt = (lane < 8) ? t - (XPR-1) : 0;
        } else {                               // l0h(t+1) ready + Xp1 ring space
          if (lane < 16){ fi = lane; tgt = t+1; }
          else if (lane < 24){ fi = 16 + d*8 + (lane-16); tgt = t - (XPR-1); }
          else { fi = 0; tgt = 0; }
        }
        while (1){ int v = fld(flags, fi); if (__all(v >= tgt)) break;
                   __builtin_amdgcn_s_sleep(1); }
      }
      if (!isl1 && tid < 64) stok[tid] = ctx[tid*200 + t];
      __syncthreads();
      // stage X: 64x768 bf16 into lact (stride 776)
      if (!isl1){
#pragma unroll
        for (int r=0;r<24;r++){                // emb gather: cached loads
          int e = r*2048 + tid*8;
          int rowi = e/768, off = e%768;
          stage8(&lact[rowi*776 + off], emb, (long)stok[rowi]*768 + off, mode);
        }
      } else {
        const long hb = (long)((t+1) % L0HR)*TSLOT;
#pragma unroll
        for (int r=0;r<24;r++){                // l0h ring: coherent loads
          int e = r*2048 + tid*8;
          int rowi = e/768, off = e%768;
          const u16* s = l0h + hb + (long)rowi*768 + off;
          u64 v0 = cohld(s), v1 = cohld(s+4);
          *(u64*)&lact[rowi*776+off] = v0; *(u64*)&lact[rowi*776+off+4] = v1;
        }
      }
      __syncthreads();
      f32x4 acc[2][4];
#pragma unroll
      for (int Mt=0;Mt<2;Mt++)
#pragma unroll
        for (int Nt=0;Nt<4;Nt++) acc[Mt][Nt] = (f32x4){0.f,0.f,0.f,0.f};
#pragma unroll
      for (int ks=0;ks<24;ks++){
        short8 bf[4];
#pragma unroll
        for (int Nt=0;Nt<4;Nt++)
          bf[Nt] = *(const short8*)&lact[(Nt*16 + m15)*776 + ks*32 + q*8];
#pragma unroll
        for (int Mt=0;Mt<2;Mt++)
#pragma unroll
          for (int Nt=0;Nt<4;Nt++)
            acc[Mt][Nt] = MFMA16x16x32(wbh[Mt][ks], bf[Nt], acc[Mt][Nt], 0,0,0);
      }
      // write Xp[t]: bias folded, gate-major per hdim, coherent 8B stores
      {
        const long xb = (long)(t % XPR)*XPSLOT;
#pragma unroll
        for (int Mt=0;Mt<2;Mt++)
#pragma unroll
          for (int Nt=0;Nt<4;Nt++){
            union{u64 v; u16x4 h;} u;
#pragma unroll
            for (int r=0;r<4;r++) u.h[r] = f2bf(acc[Mt][Nt][r] + bias[Mt][r]);
            cohst(xpk + xb + (long)(Nt*16+m15)*1536 + (j0h + Mt*4 + q)*4, u.v);
          }
      }
      __syncthreads();                         // vmcnt drain: release order
      if (tid==0) fst(flags, selfF, t+1);
    }
  }
}

// ---- K4: classifier head over the fp32 target rows already in out ----------
__global__ __launch_bounds__(64) void k4_out(
    const void* __restrict__ wcls, const void* __restrict__ bcls,
    const int* __restrict__ wsmode, float* __restrict__ out){
  const int mode = wsmode[0];
  int b = blockIdx.x, lane = threadIdx.x;
  float a0=0.f, a1=0.f;
#pragma unroll
  for (int ch=0; ch<12; ++ch){
    int e = ch*64 + lane;
    float xv = out[256 + b*768 + e];
    a0 += xv * lds1(wcls, e, mode);
    a1 += xv * lds1(wcls, 768 + e, mode);
  }
#pragma unroll
  for (int off=32; off>0; off>>=1){
    a0 += __shfl_down(a0, off);
    a1 += __shfl_down(a1, off);
  }
  if (lane==0){
    float l0v = a0 + lds1(bcls, 0, mode);
    float l1v = a1 + lds1(bcls, 1, mode);
    out[b*2+0]     = l0v;                      // logits, fp32
    out[b*2+1]     = l1v;
    out[128+b*2+0] = sigf(l0v);                // probs, fp32
    out[128+b*2+1] = sigf(l1v);
  }
}

extern "C" void kernel_launch(void* const* d_in, const int* in_sizes, int n_in,
                              void* d_out, int out_size, void* d_ws, size_t ws_size,
                              hipStream_t stream){
  (void)in_sizes; (void)n_in; (void)out_size; (void)ws_size;
  const int* ctx  = (const int*)d_in[0];
  const int* pos  = (const int*)d_in[1];
  const void* emb = d_in[2];
  const void* wih = d_in[3];
  const void* whh = d_in[4];
  const void* blst= d_in[5];
  const void* wcls= d_in[6];
  const void* bcls= d_in[7];
  char* ws = (char*)d_ws;
  int* wsmode = (int*)ws;
  int* flags  = (int*)(ws + WS_FLAGS);
  u16* xp     = (u16*)(ws + WS_XP);
  u16* l0h    = (u16*)(ws + WS_L0H);
  u16* l1r    = (u16*)(ws + WS_L1R);
  float* out  = (float*)d_out;
  hipLaunchKernelGGL(kdet, dim3(1), dim3(256), 0, stream,
                     (const unsigned int*)emb, wsmode);
  hipLaunchKernelGGL(k0_init, dim3(96), dim3(256), 0, stream,
                     (unsigned int*)l0h, (unsigned int*)l1r, flags);
  hipLaunchKernelGGL(k3_lstm, dim3(80), dim3(256), 0, stream,
                     wih, whh, blst, emb, ctx, pos, xp, l0h, l1r, flags, wsmode, out);
  hipLaunchKernelGGL(k4_out, dim3(64), dim3(64), 0, stream, wcls, bcls, wsmode, out);
}

// Round 8
// 2073.436 us; speedup vs baseline: 2.5434x; 1.6539x over previous
//
#include <hip/hip_runtime.h>
#include <stdint.h>

typedef unsigned short u16;
typedef unsigned long long u64;
typedef short short8 __attribute__((ext_vector_type(8)));
typedef unsigned short u16x4 __attribute__((ext_vector_type(4)));
typedef unsigned short u16x8 __attribute__((ext_vector_type(8)));
typedef float f32x4 __attribute__((ext_vector_type(4)));

#define MFMA16x16x32 __builtin_amdgcn_mfma_f32_16x16x32_bf16

#define TSLOT   49152L     // u16 per h/x time-slot (64 x 768)
#define XPSLOT  98304L     // u16 per Xp time-slot per kidx (64 x 1536)
#define XRNG    32         // Xp ring depth (power of 2)

// ws byte layout (write-once history + small rings; total ~84.4 MB)
#define WS_FLAGS 256L                              // 128 flags x 128B
#define WS_XSTG  16640L                            // Xstage: 200 slots
#define WS_XP0   (WS_XSTG + 200L*TSLOT*2)          // Xp0: 2 dirs x 32-ring
#define WS_XP1   (WS_XP0 + 2L*XRNG*XPSLOT*2)
#define WS_L0H   (WS_XP1 + 2L*XRNG*XPSLOT*2)      // l0 h history: 201 slots
#define WS_L1H   (WS_L0H + 201L*TSLOT*2)           // l1 h history: 201 slots

static __device__ __forceinline__ float bf2f(u16 u){
  union{unsigned int i; float f;} v; v.i=((unsigned int)u)<<16; return v.f;
}
static __device__ __forceinline__ u16 f2bf(float f){
  union{float f; unsigned int i;} v; v.f=f;
  return (u16)((v.i + 0x7fffu + ((v.i>>16)&1u))>>16);   // RNE
}
static __device__ __forceinline__ float sigf(float x){
  return __fdividef(1.f, 1.f + __expf(-x));
}
static __device__ __forceinline__ float tanh_(float x){
  return 1.f - __fdividef(2.f, __expf(2.f*x) + 1.f);
}
// coherent (agent-scope, cache-bypassing): ONLY for ring slices, h writes, flags
static __device__ __forceinline__ u64 cohld(const u16* p){
  return __hip_atomic_load((const u64*)p, __ATOMIC_RELAXED, __HIP_MEMORY_SCOPE_AGENT);
}
static __device__ __forceinline__ void cohst(u16* p, u64 v){
  __hip_atomic_store((u64*)p, v, __ATOMIC_RELAXED, __HIP_MEMORY_SCOPE_AGENT);
}
static __device__ __forceinline__ int fld(const int* flags, int fi){
  return __hip_atomic_load(&flags[fi*32], __ATOMIC_RELAXED, __HIP_MEMORY_SCOPE_AGENT);
}
static __device__ __forceinline__ void fst(int* flags, int fi, int v){
  __hip_atomic_store(&flags[fi*32], v, __ATOMIC_RELAXED, __HIP_MEMORY_SCOPE_AGENT);
}
// mode: 1 = tensor is fp32 (convert on load), 0 = tensor is bf16
static __device__ __forceinline__ short8 ldw8(const void* base, long e, int mode){
  if (mode==0) return *(const short8*)((const u16*)base + e);
  const float* p = (const float*)base + e;
  float4 a = *(const float4*)p, b = *(const float4*)(p+4);
  short8 r; r[0]=(short)f2bf(a.x); r[1]=(short)f2bf(a.y); r[2]=(short)f2bf(a.z); r[3]=(short)f2bf(a.w);
  r[4]=(short)f2bf(b.x); r[5]=(short)f2bf(b.y); r[6]=(short)f2bf(b.z); r[7]=(short)f2bf(b.w);
  return r;
}
static __device__ __forceinline__ float lds1(const void* base, long e, int mode){
  return mode ? ((const float*)base)[e] : bf2f(((const u16*)base)[e]);
}

// ---- Kd: dtype detection on raw W_emb words (fp32 vs bf16) -----------------
__global__ void kdet(const unsigned int* __restrict__ w, int* wsmode){
  __shared__ int sh[256];
  int c = 0;
  for (int i=threadIdx.x; i<4096; i+=256){
    unsigned int x = w[i] & 0xFFFFu;
    if (((x>>7)&0xFFu) >= 0x80u) c++;
  }
  sh[threadIdx.x]=c; __syncthreads();
  for (int s=128;s>0;s>>=1){
    if (threadIdx.x<s) sh[threadIdx.x]+=sh[threadIdx.x+s];
    __syncthreads();
  }
  if (threadIdx.x==0) wsmode[0] = (sh[0] > 256) ? 1 : 0;
}

// ---- K0: zero h slot-0s + flags --------------------------------------------
__global__ void k0_init(unsigned int* l0h, unsigned int* l1h, int* flags){
  int i = blockIdx.x*256 + threadIdx.x;       // 96*256 = 24576
  l0h[i] = 0u;                                // l0h slot 0 (24576 dwords)
  l1h[i] = 0u;                                // l1h slot 0
  if (i < 4096) flags[i] = 0;                 // 128 flags, 128B-strided
}

// ---- Kx: Xstage[t][b][0:768] = emb[ctx[b][t]] as bf16 (gather ONCE) --------
// Normal stores; kernel-boundary release makes it cached-read-safe in k3.
__global__ __launch_bounds__(256) void kx(
    const void* __restrict__ emb, const int* __restrict__ ctx,
    const int* __restrict__ wsmode, u16* __restrict__ xstg){
  const int mode = wsmode[0];
  long f = ((long)blockIdx.x*256 + threadIdx.x)*8;   // u16 flat index
  long row = f / 768;  int col = (int)(f % 768);
  int t = (int)(row >> 6), b = (int)(row & 63);
  long token = ctx[b*200 + t];
  if (mode){
    const float* p = (const float*)emb + token*768 + col;
    float4 a = *(const float4*)p, bb = *(const float4*)(p+4);
    u16x8 v; v[0]=f2bf(a.x); v[1]=f2bf(a.y); v[2]=f2bf(a.z); v[3]=f2bf(a.w);
    v[4]=f2bf(bb.x); v[5]=f2bf(bb.y); v[6]=f2bf(bb.z); v[7]=f2bf(bb.w);
    *(u16x8*)(xstg + f) = v;
  } else {
    *(u16x8*)(xstg + f) = *(const u16x8*)((const u16*)emb + token*768 + col);
  }
}

// ---- K3: 128 persistent WGs -------------------------------------------------
// wg 0..15  l0 chains (d=wg>>3, slot=wg&7): 48 hdims each; K=384 recurrence.
// wg 16..31 l1 chains.
// wg 32..79 Xp0 producers: d=(wg-32)/24, r=..%24: phase=r/12 (t mod 2), slice=r%12.
//           Xp0[t] = Xstage[t] @ Wih_d^T + b_d   (K=768, cached input reads)
// wg 80..127 Xp1 producers: Xp1[t] = l0h[t+1] @ Wih^T + b (cached input reads).
// Coherence rules: history buffers (Xstage/l0h/l1h) are write-once => cached
// 16B reads after flag are safe (dispatch-start L2 invalidate + sc1 writes
// reach LLC before flag). Xp rings are read via coherent 8B slice loads only.
__global__ __launch_bounds__(256,1) void k3_lstm(
    const void* __restrict__ wih, const void* __restrict__ whh,
    const void* __restrict__ blstm, const int* __restrict__ pos,
    const u16* __restrict__ xstg, u16* __restrict__ xp0, u16* __restrict__ xp1,
    u16* __restrict__ l0h, u16* __restrict__ l1h,
    int* flags, const int* __restrict__ wsmode, float* __restrict__ out){
  __shared__ __align__(16) u16 lact[64*776];
  __shared__ __align__(16) u16 hstage[64*48];
  __shared__ int spos[64];
  const int mode = wsmode[0];
  const int tid = threadIdx.x, lane = tid & 63, w = tid >> 6;
  const int m15 = lane & 15, q = lane >> 4;
  const int g = m15 & 3, hl = m15 >> 2;        // A-row m15 -> (gate, hdim)
  const int wg = blockIdx.x;

  if (wg < 32){
    // ================= chain WG =================
    const int layer = wg >> 4, x = wg & 15, d = x >> 3, slot = x & 7;
    const int kidx = 2*layer + d;
    const int j0 = slot*48 + w*12;             // 12 hdims (3 Mtiles)
    const void* whhd = mode ? (const void*)((const float*)whh + (long)kidx*1536*384)
                            : (const void*)((const u16*)whh + (long)kidx*1536*384);
    short8 wa[3][12];
#pragma unroll
    for (int Mt=0;Mt<3;Mt++){
      long row = (long)g*384 + j0 + Mt*4 + hl;
#pragma unroll
      for (int ks=0;ks<12;ks++)
        wa[Mt][ks] = ldw8(whhd, row*384 + ks*32 + q*8, mode);
    }
    if (tid < 64) spos[tid] = pos[tid];
    u16* xpk  = (layer ? xp1 : xp0) + (long)d*XRNG*XPSLOT;
    u16* hbuf = layer ? l1h : l0h;
    const int selfF = wg;
    const int peerB = layer*16 + d*8;
    const int prodB = (layer ? 80 : 32) + d*24;
    float cst[3][4];
#pragma unroll
    for(int i=0;i<3;i++)
#pragma unroll
      for(int j=0;j<4;j++) cst[i][j]=0.f;

    for (int t=0;t<200;++t){
      if (w==0){
        int fi, tgt;
        if (lane < 8){ fi = peerB + lane; tgt = t; }                   // peers: h[t]
        else if (lane < 20){ fi = prodB + (t&1)*12 + (lane-8); tgt = t+1; } // Xp[t]
        else { fi = 0; tgt = 0; }
        while (1){ int v = fld(flags, fi); if (__all(v >= tgt)) break;
                   __builtin_amdgcn_s_sleep(1); }
      }
      __syncthreads();
      // acc-init: Xp ring slices, coherent 8B (never cached)
      u64 xr[3][4];
      const long xb = (long)(t & (XRNG-1))*XPSLOT;
#pragma unroll
      for (int Mt=0;Mt<3;Mt++)
#pragma unroll
        for (int Nt=0;Nt<4;Nt++)
          xr[Mt][Nt] = cohld(xpk + xb + (long)(Nt*16+m15)*1536 + (j0+Mt*4+q)*4);
      // stage own-dir h[t]: 64x384 bf16, CACHED 16B (write-once history)
      {
        const long hb = (long)t*TSLOT;
#pragma unroll
        for (int r=0;r<12;r++){
          int flat = r*4096 + tid*16;          // byte offset within 64x768B
          int rowi = flat/768, off = (flat%768)>>1;
          *(u16x8*)&lact[rowi*392+off] =
            *(const u16x8*)(hbuf + hb + (long)rowi*768 + d*384 + off);
        }
      }
      __syncthreads();
      f32x4 acc[3][4];
#pragma unroll
      for (int Mt=0;Mt<3;Mt++)
#pragma unroll
        for (int Nt=0;Nt<4;Nt++){
          union{u64 v; u16x4 h;} u; u.v = xr[Mt][Nt];
          acc[Mt][Nt] = (f32x4){ bf2f(u.h[0]), bf2f(u.h[1]), bf2f(u.h[2]), bf2f(u.h[3]) };
        }
#pragma unroll
      for (int ks=0;ks<12;ks++){
        short8 bf[4];
#pragma unroll
        for (int Nt=0;Nt<4;Nt++)
          bf[Nt] = *(const short8*)&lact[(Nt*16 + m15)*392 + ks*32 + q*8];
#pragma unroll
        for (int Mt=0;Mt<3;Mt++)
#pragma unroll
          for (int Nt=0;Nt<4;Nt++)
            acc[Mt][Nt] = MFMA16x16x32(wa[Mt][ks], bf[Nt], acc[Mt][Nt], 0,0,0);
      }
#pragma unroll
      for (int Mt=0;Mt<3;Mt++)
#pragma unroll
        for (int Nt=0;Nt<4;Nt++){
          float gi = sigf(acc[Mt][Nt][0]);     // bias folded into Xp
          float gf = sigf(acc[Mt][Nt][1]);
          float gz = tanh_(acc[Mt][Nt][2]);
          float go = sigf(acc[Mt][Nt][3]);
          float c2 = gf*cst[Mt][Nt] + gi*gz;   // c stays fp32 in registers
          cst[Mt][Nt] = c2;
          float hn = go*tanh_(c2);
          hstage[(Nt*16 + m15)*48 + (w*12 + Mt*4 + q)] = f2bf(hn);
          if (layer==1 && spos[Nt*16 + m15] == t)
            out[256 + (Nt*16 + m15)*768 + d*384 + slot*48 + w*12 + Mt*4 + q] = hn;
        }
      __syncthreads();
      {                                        // h[t+1] write-through: 64x48 bf16
        const long ob = (long)(t+1)*TSLOT;
#pragma unroll
        for (int s2=0;s2<3;s2++){
          int flat = tid*24 + s2*8;
          int b = flat/96, off = (flat%96)>>1;
          cohst(hbuf + ob + (long)b*768 + d*384 + slot*48 + off,
                *(const u64*)&hstage[b*48 + off]);
        }
      }
      __syncthreads();                         // vmcnt drain: release order
      if (tid==0) fst(flags, selfF, t+1);
    }
  } else {
    // ================= Xp producer WG =================
    const int isl1 = (wg >= 80);
    const int pidx = wg - (isl1 ? 80 : 32);
    const int d = pidx / 24, r24 = pidx % 24;
    const int phase = r24 / 12, slice = r24 % 12;
    const int kidx = isl1 ? 2 + d : d;
    const int j0h = slice*32 + w*8;            // 8 hdims (2 Mtiles)
    const void* wihd = mode ? (const void*)((const float*)wih + (long)kidx*1536*768)
                            : (const void*)((const u16*)wih + (long)kidx*1536*768);
    short8 wbh[2][24];
#pragma unroll
    for (int Mt=0;Mt<2;Mt++){
      long row = (long)g*384 + j0h + Mt*4 + hl;
#pragma unroll
      for (int ks=0;ks<24;ks++)
        wbh[Mt][ks] = ldw8(wihd, row*768 + ks*32 + q*8, mode);
    }
    float bias[2][4];
#pragma unroll
    for (int Mt=0;Mt<2;Mt++)
#pragma unroll
      for (int r=0;r<4;r++)
        bias[Mt][r] = lds1(blstm, (long)kidx*1536 + r*384 + j0h + Mt*4 + q, mode);
    u16* xpk = (isl1 ? xp1 : xp0) + (long)d*XRNG*XPSLOT;
    const int selfF = wg;
    const int chainB = isl1 ? 16 + d*8 : d*8;

    for (int t=phase; t<200; t+=2){
      if (w==0){
        int fi, tgt;
        if (lane < 8){ fi = chainB + lane; tgt = t - (XRNG-1); }       // ring space
        else if (isl1 && lane < 24){ fi = lane - 8; tgt = t+1; }       // l0h[t+1]
        else { fi = 0; tgt = 0; }
        while (1){ int v = fld(flags, fi); if (__all(v >= tgt)) break;
                   __builtin_amdgcn_s_sleep(1); }
      }
      __syncthreads();
      // stage input 64x768 bf16: CACHED 16B (Xstage or l0h history)
      {
        const u16* src = isl1 ? (l0h + (long)(t+1)*TSLOT) : (xstg + (long)t*TSLOT);
#pragma unroll
        for (int r=0;r<24;r++){
          int e = r*2048 + tid*8;              // u16 element index
          int rowi = e/768, off = e%768;
          *(u16x8*)&lact[rowi*776 + off] = *(const u16x8*)(src + (long)rowi*768 + off);
        }
      }
      __syncthreads();
      f32x4 acc[2][4];
#pragma unroll
      for (int Mt=0;Mt<2;Mt++)
#pragma unroll
        for (int Nt=0;Nt<4;Nt++) acc[Mt][Nt] = (f32x4){0.f,0.f,0.f,0.f};
#pragma unroll
      for (int ks=0;ks<24;ks++){
        short8 bf[4];
#pragma unroll
        for (int Nt=0;Nt<4;Nt++)
          bf[Nt] = *(const short8*)&lact[(Nt*16 + m15)*776 + ks*32 + q*8];
#pragma unroll
        for (int Mt=0;Mt<2;Mt++)
#pragma unroll
          for (int Nt=0;Nt<4;Nt++)
            acc[Mt][Nt] = MFMA16x16x32(wbh[Mt][ks], bf[Nt], acc[Mt][Nt], 0,0,0);
      }
      {                                        // Xp[t] slices: coherent 8B stores
        const long xb = (long)(t & (XRNG-1))*XPSLOT;
#pragma unroll
        for (int Mt=0;Mt<2;Mt++)
#pragma unroll
          for (int Nt=0;Nt<4;Nt++){
            union{u64 v; u16x4 h;} u;
#pragma unroll
            for (int r=0;r<4;r++) u.h[r] = f2bf(acc[Mt][Nt][r] + bias[Mt][r]);
            cohst(xpk + xb + (long)(Nt*16+m15)*1536 + (j0h + Mt*4 + q)*4, u.v);
          }
      }
      __syncthreads();                         // vmcnt drain: release order
      if (tid==0) fst(flags, selfF, t+1);
    }
  }
}

// ---- K4: classifier head over the fp32 target rows already in out ----------
__global__ __launch_bounds__(64) void k4_out(
    const void* __restrict__ wcls, const void* __restrict__ bcls,
    const int* __restrict__ wsmode, float* __restrict__ out){
  const int mode = wsmode[0];
  int b = blockIdx.x, lane = threadIdx.x;
  float a0=0.f, a1=0.f;
#pragma unroll
  for (int ch=0; ch<12; ++ch){
    int e = ch*64 + lane;
    float xv = out[256 + b*768 + e];
    a0 += xv * lds1(wcls, e, mode);
    a1 += xv * lds1(wcls, 768 + e, mode);
  }
#pragma unroll
  for (int off=32; off>0; off>>=1){
    a0 += __shfl_down(a0, off);
    a1 += __shfl_down(a1, off);
  }
  if (lane==0){
    float l0v = a0 + lds1(bcls, 0, mode);
    float l1v = a1 + lds1(bcls, 1, mode);
    out[b*2+0]     = l0v;                      // logits, fp32
    out[b*2+1]     = l1v;
    out[128+b*2+0] = sigf(l0v);                // probs, fp32
    out[128+b*2+1] = sigf(l1v);
  }
}

extern "C" void kernel_launch(void* const* d_in, const int* in_sizes, int n_in,
                              void* d_out, int out_size, void* d_ws, size_t ws_size,
                              hipStream_t stream){
  (void)in_sizes; (void)n_in; (void)out_size; (void)ws_size;
  const int* ctx  = (const int*)d_in[0];
  const int* pos  = (const int*)d_in[1];
  const void* emb = d_in[2];
  const void* wih = d_in[3];
  const void* whh = d_in[4];
  const void* blst= d_in[5];
  const void* wcls= d_in[6];
  const void* bcls= d_in[7];
  char* ws = (char*)d_ws;
  int* wsmode = (int*)ws;
  int* flags  = (int*)(ws + WS_FLAGS);
  u16* xstg   = (u16*)(ws + WS_XSTG);
  u16* xp0    = (u16*)(ws + WS_XP0);
  u16* xp1    = (u16*)(ws + WS_XP1);
  u16* l0h    = (u16*)(ws + WS_L0H);
  u16* l1h    = (u16*)(ws + WS_L1H);
  float* out  = (float*)d_out;
  hipLaunchKernelGGL(kdet, dim3(1), dim3(256), 0, stream,
                     (const unsigned int*)emb, wsmode);
  hipLaunchKernelGGL(k0_init, dim3(96), dim3(256), 0, stream,
                     (unsigned int*)l0h, (unsigned int*)l1h, flags);
  hipLaunchKernelGGL(kx, dim3(4800), dim3(256), 0, stream, emb, ctx, wsmode, xstg);
  hipLaunchKernelGGL(k3_lstm, dim3(128), dim3(256), 0, stream,
                     wih, whh, blst, pos, xstg, xp0, xp1, l0h, l1h, flags, wsmode, out);
  hipLaunchKernelGGL(k4_out, dim3(64), dim3(64), 0, stream, wcls, bcls, wsmode, out);
}